// Round 8
// baseline (3573.426 us; speedup 1.0000x reference)
//
#include <hip/hip_runtime.h>
#include <hip/hip_bf16.h>
#include <stdint.h>

// GRU: B=256, S=512, E=256, H=512, C=128
// 16 teams x 16 WGs (tm = wg&15, cu = wg>>4). Team covers batch rows
// [16tm,16tm+16); member cu owns h dims [32cu,32cu+32). 4 waves/WG k-split the
// fused K=768 ([x_t | h] @ [W_ih|W_hh]^T); W slice lives in VGPRs (144/lane).
// Protocol = PROVEN R2 (sc0 sc1 device-scope loads/stores through MALL), with
// ONE structural delta: PER-WAVE flags (64/team). A wave posts flag
// [cu*4+wv]=t+2 right after ITS OWN vmcnt(0) store-drain (no barrier E); every
// wave polls all 64 flags (lane l <-> producer wave l), so loads need no
// barrier A either. Remaining barriers: B (staging->MFMA) and D (cbuf->combine)
// also provide the cross-round LDS write/read separation (staging(t) writes vs
// MFMA(t-1) reads are ordered by D(t-1); cb reuse by B/D). FP math order is
// R2-identical => absmax must reproduce.

typedef __attribute__((ext_vector_type(8))) short bf16x8;
typedef __attribute__((ext_vector_type(4))) float f32x4;

#define SWZ(r) (((r)&7) << 4)

static __device__ __forceinline__ unsigned short f2bf(float f) {
  unsigned x = __builtin_bit_cast(unsigned, f);
  return (unsigned short)((x + 0x7fffu + ((x >> 16) & 1u)) >> 16);  // RNE
}
static __device__ __forceinline__ float bf2f(unsigned u) {
  return __builtin_bit_cast(float, u << 16);
}
static __device__ __forceinline__ void st_sys_u32(void* p, unsigned v) {
  asm volatile("global_store_dword %0, %1, off sc0 sc1" :: "v"(p), "v"(v) : "memory");
}

__global__ __launch_bounds__(256, 1) void gru_persistent(
    const float* __restrict__ x, const float* __restrict__ h0,
    const float* __restrict__ Wih, const float* __restrict__ Whh,
    const float* __restrict__ bih, const float* __restrict__ bhh,
    unsigned* __restrict__ flags, unsigned short* __restrict__ hbuf) {
  // per-row 1536B: [0,512) x_t bf16 swizzled; [512,1536) h bf16 swizzled.
  __shared__ __align__(16) char ldsb[16 * 1536];
  __shared__ __align__(16) float cb[4 * 4 * 2 * 256];  // [wave][type][nf][row*16+col]

  const int tid = threadIdx.x, wg = blockIdx.x;
  const int tm = wg & 15, cu = wg >> 4;
  const int wv = tid >> 6, ln = tid & 63;
  const int bm = tm << 4;   // batch base
  const int d0 = cu << 5;   // h-dim slice base (32 dims)

  unsigned* tfl = flags + tm * 64;       // 64 per-wave flags/team (256B)
  const unsigned* fp = tfl + ln;         // lane l polls producer wave l
  unsigned* myfl = tfl + (cu << 2) + wv; // this wave's flag
  char* hs0 = (char*)hbuf + (size_t)tm * 16384;
  char* hs1 = (char*)hbuf + 262144 + (size_t)tm * 16384;

  // ---- W slice -> VGPR bf16 B-frags (once) ----
  bf16x8 BF[3][2][6];
  {
    const int j = ln & 15, kg = ln >> 4;
#pragma unroll
    for (int g = 0; g < 3; ++g)
#pragma unroll
      for (int nf = 0; nf < 2; ++nf)
#pragma unroll
        for (int ks = 0; ks < 6; ++ks) {
          const int R = g * 512 + d0 + nf * 16 + j;
          const int k = 192 * wv + 32 * ks + 8 * kg;
          const float* src = (k < 256) ? Wih + (size_t)R * 256 + k
                                       : Whh + (size_t)R * 512 + (k - 256);
          bf16x8 v;
#pragma unroll
          for (int i = 0; i < 8; ++i) v[i] = (short)f2bf(src[i]);
          BF[g][nf][ks] = v;
        }
  }

  const int dl = tid & 15, rr = tid >> 4;
  const int dd0 = d0 + dl, dd1 = d0 + 16 + dl;
  const float bR0 = bih[dd0] + bhh[dd0], bR1 = bih[dd1] + bhh[dd1];
  const float bZ0 = bih[512 + dd0] + bhh[512 + dd0], bZ1 = bih[512 + dd1] + bhh[512 + dd1];
  const float bNx0 = bih[1024 + dd0], bNx1 = bih[1024 + dd1];
  const float bNh0 = bhh[1024 + dd0], bNh1 = bhh[1024 + dd1];

  float hr0 = h0[(size_t)(bm + rr) * 512 + dd0];
  float hr1 = h0[(size_t)(bm + rr) * 512 + dd1];

  // ---- h(0) -> hbuf slot0 (pre-swizzled, pair-packed, device-scope) ----
  {
    unsigned a0 = f2bf(hr0), a1 = f2bf(hr1);
    unsigned p0 = __shfl_xor(a0, 1, 64), p1 = __shfl_xor(a1, 1, 64);
    if (!(dl & 1)) {
      st_sys_u32(hs0 + rr * 1024 + ((2 * dd0) ^ SWZ(rr)), a0 | (p0 << 16));
      st_sys_u32(hs0 + rr * 1024 + ((2 * dd1) ^ SWZ(rr)), a1 | (p1 << 16));
    }
  }
  // ---- x(0) prefetch: thread covers row tid>>4, floats [16*(tid&15), +16) ----
  const int xr = tid >> 4, xi = tid & 15;
  f32x4 xv[4];
  {
    const float* xb = x + ((size_t)(bm + xr) * 512 + 0) * 256 + xi * 16;
#pragma unroll
    for (int q = 0; q < 4; ++q) xv[q] = *(const f32x4*)(xb + 4 * q);
  }
  asm volatile("s_waitcnt vmcnt(0)" ::: "memory");  // this wave's h0 stores acked
  if (ln == 0) st_sys_u32(myfl, 1u);                // per-wave certify h(0)

  for (int t = 0; t < 512; ++t) {
    // ---- poll: all 64 producer-wave flags >= t+1 (every wave independently) ----
    const unsigned tgt = (unsigned)(t + 1);
    while (true) {
      unsigned fv;
      asm volatile("global_load_dword %0, %1, off sc0 sc1\n\ts_waitcnt vmcnt(0)"
                   : "=v"(fv) : "v"(fp) : "memory");
      if (__ballot(fv >= tgt) == ~0ull) break;
    }

    // ---- issue h(t) device-scope loads, stage x(t) under their RT ----
    const char* hsrc = (t & 1) ? hs1 : hs0;
    f32x4 t0, t1, t2, t3;
    asm volatile("global_load_dwordx4 %0, %1, off sc0 sc1"
                 : "=v"(t0) : "v"(hsrc + (wv * 4 + 0) * 1024 + ln * 16) : "memory");
    asm volatile("global_load_dwordx4 %0, %1, off sc0 sc1"
                 : "=v"(t1) : "v"(hsrc + (wv * 4 + 1) * 1024 + ln * 16) : "memory");
    asm volatile("global_load_dwordx4 %0, %1, off sc0 sc1"
                 : "=v"(t2) : "v"(hsrc + (wv * 4 + 2) * 1024 + ln * 16) : "memory");
    asm volatile("global_load_dwordx4 %0, %1, off sc0 sc1"
                 : "=v"(t3) : "v"(hsrc + (wv * 4 + 3) * 1024 + ln * 16) : "memory");
    {
      char* rowb = ldsb + xr * 1536;
      bf16x8 xa, xc;
#pragma unroll
      for (int q = 0; q < 4; ++q) {
        xa[q] = (short)f2bf(xv[0][q]); xa[4 + q] = (short)f2bf(xv[1][q]);
        xc[q] = (short)f2bf(xv[2][q]); xc[4 + q] = (short)f2bf(xv[3][q]);
      }
      *(bf16x8*)(rowb + ((32 * xi) ^ SWZ(xr))) = xa;
      *(bf16x8*)(rowb + ((32 * xi + 16) ^ SWZ(xr))) = xc;
    }
    asm volatile("s_waitcnt vmcnt(0)" : "+v"(t0), "+v"(t1), "+v"(t2), "+v"(t3) :: "memory");
    *(f32x4*)(ldsb + (wv * 4 + 0) * 1536 + 512 + ln * 16) = t0;
    *(f32x4*)(ldsb + (wv * 4 + 1) * 1536 + 512 + ln * 16) = t1;
    *(f32x4*)(ldsb + (wv * 4 + 2) * 1536 + 512 + ln * 16) = t2;
    *(f32x4*)(ldsb + (wv * 4 + 3) * 1536 + 512 + ln * 16) = t3;
    __syncthreads();  // B: all LDS staging done

    // ---- x(t+1) prefetch (plain loads, overlap MFMA) ----
    if (t + 1 < 512) {
      const float* xb2 = x + ((size_t)(bm + xr) * 512 + (t + 1)) * 256 + xi * 16;
#pragma unroll
      for (int q = 0; q < 4; ++q) xv[q] = *(const f32x4*)(xb2 + 4 * q);
    }

    // ---- MFMA over this wave's K range ----
    f32x4 aR[2] = {}, aZ[2] = {}, aNx[2] = {}, aNh[2] = {};
    {
      const int arow = ln & 15, kg = ln >> 4;
#pragma unroll
      for (int ks = 0; ks < 6; ++ks) {
        const int p = 384 * wv + 64 * ks + 16 * kg;
        bf16x8 a = *(const bf16x8*)(ldsb + arow * 1536 + (p ^ SWZ(arow)));
        const bool isx = (192 * wv + 32 * ks) < 256;
#pragma unroll
        for (int nf = 0; nf < 2; ++nf) {
          aR[nf] = __builtin_amdgcn_mfma_f32_16x16x32_bf16(a, BF[0][nf][ks], aR[nf], 0, 0, 0);
          aZ[nf] = __builtin_amdgcn_mfma_f32_16x16x32_bf16(a, BF[1][nf][ks], aZ[nf], 0, 0, 0);
          if (isx)
            aNx[nf] = __builtin_amdgcn_mfma_f32_16x16x32_bf16(a, BF[2][nf][ks], aNx[nf], 0, 0, 0);
          else
            aNh[nf] = __builtin_amdgcn_mfma_f32_16x16x32_bf16(a, BF[2][nf][ks], aNh[nf], 0, 0, 0);
        }
      }
    }

    // ---- partials -> cbuf ----
    {
      const int cc = ln & 15, cg = ln >> 4;
#pragma unroll
      for (int nf = 0; nf < 2; ++nf)
#pragma unroll
        for (int i = 0; i < 4; ++i) {
          const int row = cg * 4 + i;
          cb[((wv * 4 + 0) * 2 + nf) * 256 + row * 16 + cc] = aR[nf][i];
          cb[((wv * 4 + 1) * 2 + nf) * 256 + row * 16 + cc] = aZ[nf][i];
          if (wv <= 1) cb[((wv * 4 + 2) * 2 + nf) * 256 + row * 16 + cc] = aNx[nf][i];
          if (wv >= 1) cb[((wv * 4 + 3) * 2 + nf) * 256 + row * 16 + cc] = aNh[nf][i];
        }
    }
    __syncthreads();  // D

    // ---- combine + gates (fp32) ----
    {
#define CBX(w, ty, nf) cb[(((w) * 4 + (ty)) * 2 + (nf)) * 256 + rr * 16 + dl]
      float rp0 = bR0 + CBX(0,0,0) + CBX(1,0,0) + CBX(2,0,0) + CBX(3,0,0);
      float rp1 = bR1 + CBX(0,0,1) + CBX(1,0,1) + CBX(2,0,1) + CBX(3,0,1);
      float zp0 = bZ0 + CBX(0,1,0) + CBX(1,1,0) + CBX(2,1,0) + CBX(3,1,0);
      float zp1 = bZ1 + CBX(0,1,1) + CBX(1,1,1) + CBX(2,1,1) + CBX(3,1,1);
      float ix0 = bNx0 + CBX(0,2,0) + CBX(1,2,0);
      float ix1 = bNx1 + CBX(0,2,1) + CBX(1,2,1);
      float hn0 = bNh0 + CBX(1,3,0) + CBX(2,3,0) + CBX(3,3,0);
      float hn1 = bNh1 + CBX(1,3,1) + CBX(2,3,1) + CBX(3,3,1);
#undef CBX
      const float rg0 = 1.f / (1.f + __expf(-rp0)), rg1 = 1.f / (1.f + __expf(-rp1));
      const float zg0 = 1.f / (1.f + __expf(-zp0)), zg1 = 1.f / (1.f + __expf(-zp1));
      const float e0 = __expf(2.f * (ix0 + rg0 * hn0));
      const float e1 = __expf(2.f * (ix1 + rg1 * hn1));
      const float ng0 = 1.f - 2.f / (e0 + 1.f), ng1 = 1.f - 2.f / (e1 + 1.f);
      hr0 = ng0 + zg0 * (hr0 - ng0);
      hr1 = ng1 + zg1 * (hr1 - ng1);
    }

    // ---- h(t+1) -> hbuf (pair-packed u32, device-scope) ----
    {
      char* hdst = ((t + 1) & 1) ? hs1 : hs0;
      unsigned a0 = f2bf(hr0), a1 = f2bf(hr1);
      unsigned p0 = __shfl_xor(a0, 1, 64), p1 = __shfl_xor(a1, 1, 64);
      if (!(dl & 1)) {
        st_sys_u32(hdst + rr * 1024 + ((2 * dd0) ^ SWZ(rr)), a0 | (p0 << 16));
        st_sys_u32(hdst + rr * 1024 + ((2 * dd1) ^ SWZ(rr)), a1 | (p1 << 16));
      }
    }
    asm volatile("s_waitcnt vmcnt(0)" ::: "memory");  // THIS wave's h stores acked
    if (ln == 0) st_sys_u32(myfl, tgt + 1);           // per-wave certify h(t+1)
  }
}

// ---- logits + masked CE + accuracy; one WG per batch row ----
__global__ __launch_bounds__(128) void logits_loss(
    const unsigned short* __restrict__ hbuf, const float* __restrict__ Wout,
    const float* __restrict__ bout, const int* __restrict__ label,
    float* __restrict__ accv) {
  __shared__ float hrow[512];
  __shared__ float lg[128];
  const int b = blockIdx.x;
  const int tm = b >> 4, r = b & 15;
  const char* base = (const char*)hbuf + (size_t)tm * 16384 + r * 1024;
  for (int i = threadIdx.x; i < 256; i += 128) {
    const char* p = base + ((i * 4) ^ SWZ(r));
    unsigned v;
    asm volatile("global_load_dword %0, %1, off sc0 sc1\n\ts_waitcnt vmcnt(0)"
                 : "=v"(v) : "v"(p) : "memory");
    hrow[2 * i] = bf2f(v & 0xffffu);
    hrow[2 * i + 1] = bf2f(v >> 16);
  }
  __syncthreads();
  const int c = threadIdx.x;
  const f32x4* w4 = (const f32x4*)(Wout + (size_t)c * 512);
  const f32x4* h4 = (const f32x4*)hrow;
  float s = bout[c];
#pragma unroll 4
  for (int i = 0; i < 128; ++i) {
    f32x4 wv = w4[i], hv = h4[i];
    s += wv[0] * hv[0] + wv[1] * hv[1] + wv[2] * hv[2] + wv[3] * hv[3];
  }
  lg[c] = s;
  __syncthreads();
  if (c == 0) {
    float mx = lg[0];
    int am = 0;
    for (int i = 1; i < 128; ++i)
      if (lg[i] > mx) { mx = lg[i]; am = i; }
    float se = 0.f;
    for (int i = 0; i < 128; ++i) se += __expf(lg[i] - mx);
    const int lb = label[b];
    const float logp = lg[lb] - mx - __logf(se);
    if (lb != 0) {
      atomicAdd(&accv[0], -logp);
      atomicAdd(&accv[1], 1.0f);
    }
    if (am == lb) atomicAdd(&accv[2], 1.0f);
  }
}

__global__ void finalize_k(const float* __restrict__ accv, float* __restrict__ out) {
  out[0] = accv[0] / fmaxf(accv[1], 1.0f);
  out[1] = accv[2] * (1.0f / 256.0f);
}

extern "C" void kernel_launch(void* const* d_in, const int* in_sizes, int n_in,
                              void* d_out, int out_size, void* d_ws, size_t ws_size,
                              hipStream_t stream) {
  (void)in_sizes; (void)n_in; (void)out_size; (void)ws_size;
  const float* x = (const float*)d_in[0];
  const int* label = (const int*)d_in[1];
  const float* h0 = (const float*)d_in[2];
  const float* Wih = (const float*)d_in[3];
  const float* Whh = (const float*)d_in[4];
  const float* bih = (const float*)d_in[5];
  const float* bhh = (const float*)d_in[6];
  const float* Wout = (const float*)d_in[7];
  const float* bout = (const float*)d_in[8];
  float* out = (float*)d_out;

  char* ws = (char*)d_ws;
  unsigned* flags = (unsigned*)ws;                      // 16 teams x 64 u32 = 4KB
  float* accv = (float*)(ws + 4096);                    // 3 accumulators
  unsigned short* hbuf = (unsigned short*)(ws + 8192);  // 2 slots x 16 teams x 16 KB

  hipMemsetAsync(ws, 0, 8192, stream);  // flags + accv: deterministic per call

  gru_persistent<<<dim3(256), dim3(256), 0, stream>>>(x, h0, Wih, Whh, bih, bhh,
                                                      flags, hbuf);
  logits_loss<<<dim3(256), dim3(128), 0, stream>>>(hbuf, Wout, bout, label, accv);
  finalize_k<<<dim3(1), dim3(1), 0, stream>>>(accv, out);
}

// Round 9
// 2287.800 us; speedup vs baseline: 1.5619x; 1.5619x over previous
//
#include <hip/hip_runtime.h>
#include <hip/hip_bf16.h>
#include <stdint.h>

// GRU: B=256, S=512, E=256, H=512, C=128
// 16 teams x 16 WGs (tm = wg&15, cu = wg>>4). Team covers batch rows
// [16tm,16tm+16); member cu owns h dims [32cu,32cu+32). 4 waves/WG k-split the
// fused K=768 ([x_t | h] @ [W_ih|W_hh]^T); W slice lives in VGPRs (144/lane).
// Protocol = PROVEN R2 (sc0 sc1 device-scope via MALL, 16 flags/team on ONE
// 64B line). R9 deltas (all local):
//  (1) all 4 waves poll the same 16-flag line (no barrier A; each wave starts
//      its h-loads at its own detect). 4 loads/WG/round on 1 line (R8's
//      regression was 16 loads across 4 lines).
//  (2) barrier E -> per-wave vmcnt(0) + LDS ds_add; the wave reaching
//      4*(t+1)+3 posts the team flag. Own-flag dependency keeps intra-WG
//      LDS WAR ordering (a wave can't pass poll(t) until all 4 waves of its
//      WG completed combine(t-1)+stores).
//  (3) primed polls: next flag load issued right after ds_add.
// FP math order identical to R2 => absmax must reproduce 0.00390625.

typedef __attribute__((ext_vector_type(8))) short bf16x8;
typedef __attribute__((ext_vector_type(4))) float f32x4;

#define SWZ(r) (((r)&7) << 4)

static __device__ __forceinline__ unsigned short f2bf(float f) {
  unsigned x = __builtin_bit_cast(unsigned, f);
  return (unsigned short)((x + 0x7fffu + ((x >> 16) & 1u)) >> 16);  // RNE
}
static __device__ __forceinline__ float bf2f(unsigned u) {
  return __builtin_bit_cast(float, u << 16);
}
static __device__ __forceinline__ void st_sys_u32(void* p, unsigned v) {
  asm volatile("global_store_dword %0, %1, off sc0 sc1" :: "v"(p), "v"(v) : "memory");
}
static __device__ __forceinline__ void ld_sys_u32(unsigned& d, const void* p) {
  asm volatile("global_load_dword %0, %1, off sc0 sc1" : "=v"(d) : "v"(p) : "memory");
}

__global__ __launch_bounds__(256, 1) void gru_persistent(
    const float* __restrict__ x, const float* __restrict__ h0,
    const float* __restrict__ Wih, const float* __restrict__ Whh,
    const float* __restrict__ bih, const float* __restrict__ bhh,
    unsigned* __restrict__ flags, unsigned short* __restrict__ hbuf) {
  // per-row 1536B: [0,512) x_t bf16 swizzled; [512,1536) h bf16 swizzled.
  __shared__ __align__(16) char ldsb[16 * 1536];
  __shared__ __align__(16) float cb[4 * 4 * 2 * 256];  // [wave][type][nf][row*16+col]
  __shared__ unsigned scnt;  // monotone publish counter (4 adds per event)

  const int tid = threadIdx.x, wg = blockIdx.x;
  const int tm = wg & 15, cu = wg >> 4;
  const int wv = tid >> 6, ln = tid & 63;
  const int bm = tm << 4;   // batch base
  const int d0 = cu << 5;   // h-dim slice base (32 dims)

  unsigned* tfl = flags + tm * 32;      // 16 flags used (one 64B line), teams 128B apart
  const unsigned* fp = tfl + (ln & 15); // every wave polls the same line
  unsigned* myfl = tfl + cu;
  char* hs0 = (char*)hbuf + (size_t)tm * 16384;
  char* hs1 = (char*)hbuf + 262144 + (size_t)tm * 16384;

  if (tid == 0) scnt = 0;

  // ---- W slice -> VGPR bf16 B-frags (once) ----
  bf16x8 BF[3][2][6];
  {
    const int j = ln & 15, kg = ln >> 4;
#pragma unroll
    for (int g = 0; g < 3; ++g)
#pragma unroll
      for (int nf = 0; nf < 2; ++nf)
#pragma unroll
        for (int ks = 0; ks < 6; ++ks) {
          const int R = g * 512 + d0 + nf * 16 + j;
          const int k = 192 * wv + 32 * ks + 8 * kg;
          const float* src = (k < 256) ? Wih + (size_t)R * 256 + k
                                       : Whh + (size_t)R * 512 + (k - 256);
          bf16x8 v;
#pragma unroll
          for (int i = 0; i < 8; ++i) v[i] = (short)f2bf(src[i]);
          BF[g][nf][ks] = v;
        }
  }

  const int dl = tid & 15, rr = tid >> 4;
  const int dd0 = d0 + dl, dd1 = d0 + 16 + dl;
  const float bR0 = bih[dd0] + bhh[dd0], bR1 = bih[dd1] + bhh[dd1];
  const float bZ0 = bih[512 + dd0] + bhh[512 + dd0], bZ1 = bih[512 + dd1] + bhh[512 + dd1];
  const float bNx0 = bih[1024 + dd0], bNx1 = bih[1024 + dd1];
  const float bNh0 = bhh[1024 + dd0], bNh1 = bhh[1024 + dd1];

  float hr0 = h0[(size_t)(bm + rr) * 512 + dd0];
  float hr1 = h0[(size_t)(bm + rr) * 512 + dd1];

  // ---- h(0) -> hbuf slot0 (pre-swizzled, pair-packed, device-scope) ----
  {
    unsigned a0 = f2bf(hr0), a1 = f2bf(hr1);
    unsigned p0 = __shfl_xor(a0, 1, 64), p1 = __shfl_xor(a1, 1, 64);
    if (!(dl & 1)) {
      st_sys_u32(hs0 + rr * 1024 + ((2 * dd0) ^ SWZ(rr)), a0 | (p0 << 16));
      st_sys_u32(hs0 + rr * 1024 + ((2 * dd1) ^ SWZ(rr)), a1 | (p1 << 16));
    }
  }
  // ---- x(0) prefetch: thread covers row tid>>4, floats [16*(tid&15), +16) ----
  const int xr = tid >> 4, xi = tid & 15;
  f32x4 xv[4];
  {
    const float* xb = x + ((size_t)(bm + xr) * 512 + 0) * 256 + xi * 16;
#pragma unroll
    for (int q = 0; q < 4; ++q) xv[q] = *(const f32x4*)(xb + 4 * q);
  }
  __syncthreads();  // scnt=0 visible to all waves before any ds_add
  asm volatile("s_waitcnt vmcnt(0)" ::: "memory");  // this wave's h0 stores acked
  unsigned fv;
  if (ln == 0) {
    unsigned old = __hip_atomic_fetch_add(&scnt, 1u, __ATOMIC_RELAXED,
                                          __HIP_MEMORY_SCOPE_WORKGROUP);
    if (old == 3u) st_sys_u32(myfl, 1u);  // last wave certifies h(0)
  }
  ld_sys_u32(fv, fp);  // prime first poll

  for (int t = 0; t < 512; ++t) {
    // ---- poll: all waves, one flag line, primed ----
    const unsigned tgt = (unsigned)(t + 1);
    asm volatile("s_waitcnt vmcnt(0)" : "+v"(fv) :: "memory");  // drain prime
    while (__ballot(fv >= tgt) != ~0ull) {
      asm volatile("global_load_dword %0, %1, off sc0 sc1\n\ts_waitcnt vmcnt(0)"
                   : "=v"(fv) : "v"(fp) : "memory");
    }

    // ---- issue h(t) device-scope loads, stage x(t) under their RT ----
    const char* hsrc = (t & 1) ? hs1 : hs0;
    f32x4 t0, t1, t2, t3;
    asm volatile("global_load_dwordx4 %0, %1, off sc0 sc1"
                 : "=v"(t0) : "v"(hsrc + (wv * 4 + 0) * 1024 + ln * 16) : "memory");
    asm volatile("global_load_dwordx4 %0, %1, off sc0 sc1"
                 : "=v"(t1) : "v"(hsrc + (wv * 4 + 1) * 1024 + ln * 16) : "memory");
    asm volatile("global_load_dwordx4 %0, %1, off sc0 sc1"
                 : "=v"(t2) : "v"(hsrc + (wv * 4 + 2) * 1024 + ln * 16) : "memory");
    asm volatile("global_load_dwordx4 %0, %1, off sc0 sc1"
                 : "=v"(t3) : "v"(hsrc + (wv * 4 + 3) * 1024 + ln * 16) : "memory");
    {
      char* rowb = ldsb + xr * 1536;
      bf16x8 xa, xc;
#pragma unroll
      for (int q = 0; q < 4; ++q) {
        xa[q] = (short)f2bf(xv[0][q]); xa[4 + q] = (short)f2bf(xv[1][q]);
        xc[q] = (short)f2bf(xv[2][q]); xc[4 + q] = (short)f2bf(xv[3][q]);
      }
      *(bf16x8*)(rowb + ((32 * xi) ^ SWZ(xr))) = xa;
      *(bf16x8*)(rowb + ((32 * xi + 16) ^ SWZ(xr))) = xc;
    }
    asm volatile("s_waitcnt vmcnt(0)" : "+v"(t0), "+v"(t1), "+v"(t2), "+v"(t3) :: "memory");
    *(f32x4*)(ldsb + (wv * 4 + 0) * 1536 + 512 + ln * 16) = t0;
    *(f32x4*)(ldsb + (wv * 4 + 1) * 1536 + 512 + ln * 16) = t1;
    *(f32x4*)(ldsb + (wv * 4 + 2) * 1536 + 512 + ln * 16) = t2;
    *(f32x4*)(ldsb + (wv * 4 + 3) * 1536 + 512 + ln * 16) = t3;
    __syncthreads();  // B: all LDS staging done

    // ---- x(t+1) prefetch (plain loads, overlap MFMA) ----
    if (t + 1 < 512) {
      const float* xb2 = x + ((size_t)(bm + xr) * 512 + (t + 1)) * 256 + xi * 16;
#pragma unroll
      for (int q = 0; q < 4; ++q) xv[q] = *(const f32x4*)(xb2 + 4 * q);
    }

    // ---- MFMA over this wave's K range ----
    f32x4 aR[2] = {}, aZ[2] = {}, aNx[2] = {}, aNh[2] = {};
    {
      const int arow = ln & 15, kg = ln >> 4;
#pragma unroll
      for (int ks = 0; ks < 6; ++ks) {
        const int p = 384 * wv + 64 * ks + 16 * kg;
        bf16x8 a = *(const bf16x8*)(ldsb + arow * 1536 + (p ^ SWZ(arow)));
        const bool isx = (192 * wv + 32 * ks) < 256;
#pragma unroll
        for (int nf = 0; nf < 2; ++nf) {
          aR[nf] = __builtin_amdgcn_mfma_f32_16x16x32_bf16(a, BF[0][nf][ks], aR[nf], 0, 0, 0);
          aZ[nf] = __builtin_amdgcn_mfma_f32_16x16x32_bf16(a, BF[1][nf][ks], aZ[nf], 0, 0, 0);
          if (isx)
            aNx[nf] = __builtin_amdgcn_mfma_f32_16x16x32_bf16(a, BF[2][nf][ks], aNx[nf], 0, 0, 0);
          else
            aNh[nf] = __builtin_amdgcn_mfma_f32_16x16x32_bf16(a, BF[2][nf][ks], aNh[nf], 0, 0, 0);
        }
      }
    }

    // ---- partials -> cbuf ----
    {
      const int cc = ln & 15, cg = ln >> 4;
#pragma unroll
      for (int nf = 0; nf < 2; ++nf)
#pragma unroll
        for (int i = 0; i < 4; ++i) {
          const int row = cg * 4 + i;
          cb[((wv * 4 + 0) * 2 + nf) * 256 + row * 16 + cc] = aR[nf][i];
          cb[((wv * 4 + 1) * 2 + nf) * 256 + row * 16 + cc] = aZ[nf][i];
          if (wv <= 1) cb[((wv * 4 + 2) * 2 + nf) * 256 + row * 16 + cc] = aNx[nf][i];
          if (wv >= 1) cb[((wv * 4 + 3) * 2 + nf) * 256 + row * 16 + cc] = aNh[nf][i];
        }
    }
    __syncthreads();  // D

    // ---- combine + gates (fp32) ----
    {
#define CBX(w, ty, nf) cb[(((w) * 4 + (ty)) * 2 + (nf)) * 256 + rr * 16 + dl]
      float rp0 = bR0 + CBX(0,0,0) + CBX(1,0,0) + CBX(2,0,0) + CBX(3,0,0);
      float rp1 = bR1 + CBX(0,0,1) + CBX(1,0,1) + CBX(2,0,1) + CBX(3,0,1);
      float zp0 = bZ0 + CBX(0,1,0) + CBX(1,1,0) + CBX(2,1,0) + CBX(3,1,0);
      float zp1 = bZ1 + CBX(0,1,1) + CBX(1,1,1) + CBX(2,1,1) + CBX(3,1,1);
      float ix0 = bNx0 + CBX(0,2,0) + CBX(1,2,0);
      float ix1 = bNx1 + CBX(0,2,1) + CBX(1,2,1);
      float hn0 = bNh0 + CBX(1,3,0) + CBX(2,3,0) + CBX(3,3,0);
      float hn1 = bNh1 + CBX(1,3,1) + CBX(2,3,1) + CBX(3,3,1);
#undef CBX
      const float rg0 = 1.f / (1.f + __expf(-rp0)), rg1 = 1.f / (1.f + __expf(-rp1));
      const float zg0 = 1.f / (1.f + __expf(-zp0)), zg1 = 1.f / (1.f + __expf(-zp1));
      const float e0 = __expf(2.f * (ix0 + rg0 * hn0));
      const float e1 = __expf(2.f * (ix1 + rg1 * hn1));
      const float ng0 = 1.f - 2.f / (e0 + 1.f), ng1 = 1.f - 2.f / (e1 + 1.f);
      hr0 = ng0 + zg0 * (hr0 - ng0);
      hr1 = ng1 + zg1 * (hr1 - ng1);
    }

    // ---- h(t+1) -> hbuf (pair-packed u32, device-scope) ----
    {
      char* hdst = ((t + 1) & 1) ? hs1 : hs0;
      unsigned a0 = f2bf(hr0), a1 = f2bf(hr1);
      unsigned p0 = __shfl_xor(a0, 1, 64), p1 = __shfl_xor(a1, 1, 64);
      if (!(dl & 1)) {
        st_sys_u32(hdst + rr * 1024 + ((2 * dd0) ^ SWZ(rr)), a0 | (p0 << 16));
        st_sys_u32(hdst + rr * 1024 + ((2 * dd1) ^ SWZ(rr)), a1 | (p1 << 16));
      }
    }
    asm volatile("s_waitcnt vmcnt(0)" ::: "memory");  // THIS wave's h stores acked
    if (ln == 0) {
      unsigned old = __hip_atomic_fetch_add(&scnt, 1u, __ATOMIC_RELAXED,
                                            __HIP_MEMORY_SCOPE_WORKGROUP);
      if (old == 4u * (unsigned)t + 7u) st_sys_u32(myfl, tgt + 1u);  // last wave posts
    }
    ld_sys_u32(fv, fp);  // prime next poll
  }
}

// ---- logits + masked CE + accuracy; one WG per batch row ----
__global__ __launch_bounds__(128) void logits_loss(
    const unsigned short* __restrict__ hbuf, const float* __restrict__ Wout,
    const float* __restrict__ bout, const int* __restrict__ label,
    float* __restrict__ accv) {
  __shared__ float hrow[512];
  __shared__ float lg[128];
  const int b = blockIdx.x;
  const int tm = b >> 4, r = b & 15;
  const char* base = (const char*)hbuf + (size_t)tm * 16384 + r * 1024;
  for (int i = threadIdx.x; i < 256; i += 128) {
    const char* p = base + ((i * 4) ^ SWZ(r));
    unsigned v;
    asm volatile("global_load_dword %0, %1, off sc0 sc1\n\ts_waitcnt vmcnt(0)"
                 : "=v"(v) : "v"(p) : "memory");
    hrow[2 * i] = bf2f(v & 0xffffu);
    hrow[2 * i + 1] = bf2f(v >> 16);
  }
  __syncthreads();
  const int c = threadIdx.x;
  const f32x4* w4 = (const f32x4*)(Wout + (size_t)c * 512);
  const f32x4* h4 = (const f32x4*)hrow;
  float s = bout[c];
#pragma unroll 4
  for (int i = 0; i < 128; ++i) {
    f32x4 wv = w4[i], hv = h4[i];
    s += wv[0] * hv[0] + wv[1] * hv[1] + wv[2] * hv[2] + wv[3] * hv[3];
  }
  lg[c] = s;
  __syncthreads();
  if (c == 0) {
    float mx = lg[0];
    int am = 0;
    for (int i = 1; i < 128; ++i)
      if (lg[i] > mx) { mx = lg[i]; am = i; }
    float se = 0.f;
    for (int i = 0; i < 128; ++i) se += __expf(lg[i] - mx);
    const int lb = label[b];
    const float logp = lg[lb] - mx - __logf(se);
    if (lb != 0) {
      atomicAdd(&accv[0], -logp);
      atomicAdd(&accv[1], 1.0f);
    }
    if (am == lb) atomicAdd(&accv[2], 1.0f);
  }
}

__global__ void finalize_k(const float* __restrict__ accv, float* __restrict__ out) {
  out[0] = accv[0] / fmaxf(accv[1], 1.0f);
  out[1] = accv[2] * (1.0f / 256.0f);
}

extern "C" void kernel_launch(void* const* d_in, const int* in_sizes, int n_in,
                              void* d_out, int out_size, void* d_ws, size_t ws_size,
                              hipStream_t stream) {
  (void)in_sizes; (void)n_in; (void)out_size; (void)ws_size;
  const float* x = (const float*)d_in[0];
  const int* label = (const int*)d_in[1];
  const float* h0 = (const float*)d_in[2];
  const float* Wih = (const float*)d_in[3];
  const float* Whh = (const float*)d_in[4];
  const float* bih = (const float*)d_in[5];
  const float* bhh = (const float*)d_in[6];
  const float* Wout = (const float*)d_in[7];
  const float* bout = (const float*)d_in[8];
  float* out = (float*)d_out;

  char* ws = (char*)d_ws;
  unsigned* flags = (unsigned*)ws;                      // 16 teams x 32 u32 (16 used)
  float* accv = (float*)(ws + 4096);                    // 3 accumulators
  unsigned short* hbuf = (unsigned short*)(ws + 8192);  // 2 slots x 16 teams x 16 KB

  hipMemsetAsync(ws, 0, 8192, stream);  // flags + accv: deterministic per call

  gru_persistent<<<dim3(256), dim3(256), 0, stream>>>(x, h0, Wih, Whh, bih, bhh,
                                                      flags, hbuf);
  logits_loss<<<dim3(256), dim3(128), 0, stream>>>(hbuf, Wout, bout, label, accv);
  finalize_k<<<dim3(1), dim3(1), 0, stream>>>(accv, out);
}

// Round 10
// 1447.339 us; speedup vs baseline: 2.4690x; 1.5807x over previous
//
#include <hip/hip_runtime.h>
#include <hip/hip_bf16.h>
#include <stdint.h>

// GRU: B=256, S=512, E=256, H=512, C=128
// 16 teams x 16 WGs (tm = wg&15, cu = wg>>4). Team covers batch rows
// [16tm,16tm+16); member cu owns h dims [32cu,32cu+32). 4 waves/WG split the
// fused K=768 of [x_t | h] @ [W_ih|W_hh]^T; W slice in VGPRs (144/lane).
// Protocol = PROVEN R2, byte-for-byte: sc0 sc1 device-scope stores/loads via
// MALL, 16 flags/team on ONE 64B line, ONE wave polls (now wave 3), barrier
// broadcast, barriers A/B/D/E. R10 changes are work-placement only:
//  - K re-split: EVERY wave gets 2 x-frags (k = 64wv+{0,32}) + 4 h-frags
//    (k = 256+128wv+{0,32,64,96}). x-MFMA needs no h(t):
//      waves 0-2 run x-MFMA UNDER the poll; wave 3 under its h-load RT.
//    Post-stage MFMA drops 6 -> 4 frags/wave.
//  - x(t+1) staged at the tail under the store-ack shadow (x region of ldsb is
//    dead after bar D; all waves' x-MFMA(t+1) happens after bar E).
//  - primed poll for wave 3 (1 extra in-flight load; poll pressure unchanged:
//    1 wave, 1 line — R5/R8/R9 measured that more polling only hurts).
//  - sched_barrier(0) pins the x-MFMA+ds_reads before the vmcnt(0) drain so
//    they actually overlap the load RT (in-order issue; rule #18 family).
// N-gate combine now sums 4 cbuf terms (regroup only; fp32, within threshold).

typedef __attribute__((ext_vector_type(8))) short bf16x8;
typedef __attribute__((ext_vector_type(4))) float f32x4;

#define SWZ(r) (((r)&7) << 4)

static __device__ __forceinline__ unsigned short f2bf(float f) {
  unsigned x = __builtin_bit_cast(unsigned, f);
  return (unsigned short)((x + 0x7fffu + ((x >> 16) & 1u)) >> 16);  // RNE
}
static __device__ __forceinline__ float bf2f(unsigned u) {
  return __builtin_bit_cast(float, u << 16);
}
static __device__ __forceinline__ void st_sys_u32(void* p, unsigned v) {
  asm volatile("global_store_dword %0, %1, off sc0 sc1" :: "v"(p), "v"(v) : "memory");
}
static __device__ __forceinline__ void ld_sys_u32(unsigned& d, const void* p) {
  asm volatile("global_load_dword %0, %1, off sc0 sc1" : "=v"(d) : "v"(p) : "memory");
}

__global__ __launch_bounds__(256, 1) void gru_persistent(
    const float* __restrict__ x, const float* __restrict__ h0,
    const float* __restrict__ Wih, const float* __restrict__ Whh,
    const float* __restrict__ bih, const float* __restrict__ bhh,
    unsigned* __restrict__ flags, unsigned short* __restrict__ hbuf) {
  // per-row 1536B: [0,512) x_t bf16 swizzled; [512,1536) h bf16 swizzled.
  __shared__ __align__(16) char ldsb[16 * 1536];
  __shared__ __align__(16) float cb[4 * 4 * 2 * 256];  // [wave][type][nf][row*16+col]

  const int tid = threadIdx.x, wg = blockIdx.x;
  const int tm = wg & 15, cu = wg >> 4;
  const int wv = tid >> 6, ln = tid & 63;
  const int bm = tm << 4;   // batch base
  const int d0 = cu << 5;   // h-dim slice base (32 dims)

  unsigned* tfl = flags + tm * 32;       // 16 flags on one 64B line; teams 128B apart
  const unsigned* fp = tfl + (ln & 15);
  char* hs0 = (char*)hbuf + (size_t)tm * 16384;
  char* hs1 = (char*)hbuf + 262144 + (size_t)tm * 16384;

  // ---- W slice -> VGPR bf16 B-frags (once); frag f: 0-1 = x-part, 2-5 = h-part ----
  bf16x8 BF[3][2][6];
  {
    const int j = ln & 15, kg = ln >> 4;
#pragma unroll
    for (int g = 0; g < 3; ++g)
#pragma unroll
      for (int nf = 0; nf < 2; ++nf)
#pragma unroll
        for (int f = 0; f < 6; ++f) {
          const int R = g * 512 + d0 + nf * 16 + j;
          const float* src;
          if (f < 2) src = Wih + (size_t)R * 256 + (64 * wv + 32 * f + 8 * kg);
          else       src = Whh + (size_t)R * 512 + (128 * wv + 32 * (f - 2) + 8 * kg);
          bf16x8 v;
#pragma unroll
          for (int i = 0; i < 8; ++i) v[i] = (short)f2bf(src[i]);
          BF[g][nf][f] = v;
        }
  }

  const int dl = tid & 15, rr = tid >> 4;
  const int dd0 = d0 + dl, dd1 = d0 + 16 + dl;
  const float bR0 = bih[dd0] + bhh[dd0], bR1 = bih[dd1] + bhh[dd1];
  const float bZ0 = bih[512 + dd0] + bhh[512 + dd0], bZ1 = bih[512 + dd1] + bhh[512 + dd1];
  const float bNx0 = bih[1024 + dd0], bNx1 = bih[1024 + dd1];
  const float bNh0 = bhh[1024 + dd0], bNh1 = bhh[1024 + dd1];

  float hr0 = h0[(size_t)(bm + rr) * 512 + dd0];
  float hr1 = h0[(size_t)(bm + rr) * 512 + dd1];

  // ---- prologue: h(0) -> slot0; x(0) -> LDS; certify ----
  {
    unsigned a0 = f2bf(hr0), a1 = f2bf(hr1);
    unsigned p0 = __shfl_xor(a0, 1, 64), p1 = __shfl_xor(a1, 1, 64);
    if (!(dl & 1)) {
      st_sys_u32(hs0 + rr * 1024 + ((2 * dd0) ^ SWZ(rr)), a0 | (p0 << 16));
      st_sys_u32(hs0 + rr * 1024 + ((2 * dd1) ^ SWZ(rr)), a1 | (p1 << 16));
    }
  }
  const int xr = tid >> 4, xi = tid & 15;  // x staging map: row xr, floats [16xi,16xi+16)
  f32x4 xv[4];
  {
    const float* xb = x + ((size_t)(bm + xr) * 512 + 0) * 256 + xi * 16;
#pragma unroll
    for (int q = 0; q < 4; ++q) xv[q] = *(const f32x4*)(xb + 4 * q);
  }
  {
    char* rowb = ldsb + xr * 1536;
    bf16x8 xa, xc;
#pragma unroll
    for (int q = 0; q < 4; ++q) {
      xa[q] = (short)f2bf(xv[0][q]); xa[4 + q] = (short)f2bf(xv[1][q]);
      xc[q] = (short)f2bf(xv[2][q]); xc[4 + q] = (short)f2bf(xv[3][q]);
    }
    *(bf16x8*)(rowb + ((32 * xi) ^ SWZ(xr))) = xa;
    *(bf16x8*)(rowb + ((32 * xi + 16) ^ SWZ(xr))) = xc;
  }
  asm volatile("s_waitcnt vmcnt(0)" ::: "memory");  // h0 stores acked (+x loads done)
  __syncthreads();                                  // E0: stores + x(0) staged, WG-wide
  if (tid == 192) st_sys_u32(tfl + cu, 1u);         // certify h(0)
  unsigned fv = 0;
  if (wv == 3) ld_sys_u32(fv, fp);                  // prime first poll

  const int arow = ln & 15, kg = ln >> 4;

  for (int t = 0; t < 512; ++t) {
    const unsigned tgt = (unsigned)(t + 1);
    f32x4 aR[2] = {}, aZ[2] = {}, aNx[2] = {}, aNh[2] = {};

    // x-part MFMA (2 frags): reads x(t) staged before bar E of last round.
#define XPART()                                                                     \
  _Pragma("unroll")                                                                 \
  for (int fx = 0; fx < 2; ++fx) {                                                  \
    const int p = 128 * wv + 64 * fx + 16 * kg;                                     \
    bf16x8 a = *(const bf16x8*)(ldsb + arow * 1536 + (p ^ SWZ(arow)));              \
    _Pragma("unroll")                                                               \
    for (int nf = 0; nf < 2; ++nf) {                                                \
      aR[nf] = __builtin_amdgcn_mfma_f32_16x16x32_bf16(a, BF[0][nf][fx], aR[nf], 0, 0, 0); \
      aZ[nf] = __builtin_amdgcn_mfma_f32_16x16x32_bf16(a, BF[1][nf][fx], aZ[nf], 0, 0, 0); \
      aNx[nf] = __builtin_amdgcn_mfma_f32_16x16x32_bf16(a, BF[2][nf][fx], aNx[nf], 0, 0, 0); \
    }                                                                               \
  }

    if (wv == 3) {
      // poll: drain primed load, then R2's exact loop (1 wave, 1 line)
      asm volatile("s_waitcnt vmcnt(0)" : "+v"(fv) :: "memory");
      while (__ballot(fv >= tgt) != ~0ull) {
        asm volatile("global_load_dword %0, %1, off sc0 sc1\n\ts_waitcnt vmcnt(0)"
                     : "=v"(fv) : "v"(fp) : "memory");
      }
    } else {
      XPART();  // waves 0-2: x-MFMA under the poll
    }
    __syncthreads();  // A: h(t) certified for the whole WG

    // issue h(t) loads (device-scope), same mapping as R2
    const char* hsrc = (t & 1) ? hs1 : hs0;
    f32x4 t0, t1, t2, t3;
    asm volatile("global_load_dwordx4 %0, %1, off sc0 sc1"
                 : "=v"(t0) : "v"(hsrc + (wv * 4 + 0) * 1024 + ln * 16) : "memory");
    asm volatile("global_load_dwordx4 %0, %1, off sc0 sc1"
                 : "=v"(t1) : "v"(hsrc + (wv * 4 + 1) * 1024 + ln * 16) : "memory");
    asm volatile("global_load_dwordx4 %0, %1, off sc0 sc1"
                 : "=v"(t2) : "v"(hsrc + (wv * 4 + 2) * 1024 + ln * 16) : "memory");
    asm volatile("global_load_dwordx4 %0, %1, off sc0 sc1"
                 : "=v"(t3) : "v"(hsrc + (wv * 4 + 3) * 1024 + ln * 16) : "memory");

    if (wv == 3) { XPART(); }  // wave 3: x-MFMA under its own load RT
    __builtin_amdgcn_sched_barrier(0);  // pin x-MFMA/ds_reads BEFORE the drain

    asm volatile("s_waitcnt vmcnt(0)" : "+v"(t0), "+v"(t1), "+v"(t2), "+v"(t3) :: "memory");
    *(f32x4*)(ldsb + (wv * 4 + 0) * 1536 + 512 + ln * 16) = t0;
    *(f32x4*)(ldsb + (wv * 4 + 1) * 1536 + 512 + ln * 16) = t1;
    *(f32x4*)(ldsb + (wv * 4 + 2) * 1536 + 512 + ln * 16) = t2;
    *(f32x4*)(ldsb + (wv * 4 + 3) * 1536 + 512 + ln * 16) = t3;
    __syncthreads();  // B: h staged

    // x(t+1) prefetch (plain loads; compiler-managed waits; consumed at tail)
    if (t + 1 < 512) {
      const float* xb2 = x + ((size_t)(bm + xr) * 512 + (t + 1)) * 256 + xi * 16;
#pragma unroll
      for (int q = 0; q < 4; ++q) xv[q] = *(const f32x4*)(xb2 + 4 * q);
    }

    // h-part MFMA (4 frags)
#pragma unroll
    for (int fh = 0; fh < 4; ++fh) {
      const int p = 512 + 256 * wv + 64 * fh + 16 * kg;
      bf16x8 a = *(const bf16x8*)(ldsb + arow * 1536 + (p ^ SWZ(arow)));
#pragma unroll
      for (int nf = 0; nf < 2; ++nf) {
        aR[nf] = __builtin_amdgcn_mfma_f32_16x16x32_bf16(a, BF[0][nf][2 + fh], aR[nf], 0, 0, 0);
        aZ[nf] = __builtin_amdgcn_mfma_f32_16x16x32_bf16(a, BF[1][nf][2 + fh], aZ[nf], 0, 0, 0);
        aNh[nf] = __builtin_amdgcn_mfma_f32_16x16x32_bf16(a, BF[2][nf][2 + fh], aNh[nf], 0, 0, 0);
      }
    }

    // partials -> cbuf (all waves, all 4 types now)
    {
      const int cc = ln & 15, cg = ln >> 4;
#pragma unroll
      for (int nf = 0; nf < 2; ++nf)
#pragma unroll
        for (int i = 0; i < 4; ++i) {
          const int row = cg * 4 + i;
          cb[((wv * 4 + 0) * 2 + nf) * 256 + row * 16 + cc] = aR[nf][i];
          cb[((wv * 4 + 1) * 2 + nf) * 256 + row * 16 + cc] = aZ[nf][i];
          cb[((wv * 4 + 2) * 2 + nf) * 256 + row * 16 + cc] = aNx[nf][i];
          cb[((wv * 4 + 3) * 2 + nf) * 256 + row * 16 + cc] = aNh[nf][i];
        }
    }
    __syncthreads();  // D

    // combine + gates (fp32); N-gate partials now come from all 4 waves
    {
#define CBX(w, ty, nf) cb[(((w) * 4 + (ty)) * 2 + (nf)) * 256 + rr * 16 + dl]
      float rp0 = bR0 + CBX(0,0,0) + CBX(1,0,0) + CBX(2,0,0) + CBX(3,0,0);
      float rp1 = bR1 + CBX(0,0,1) + CBX(1,0,1) + CBX(2,0,1) + CBX(3,0,1);
      float zp0 = bZ0 + CBX(0,1,0) + CBX(1,1,0) + CBX(2,1,0) + CBX(3,1,0);
      float zp1 = bZ1 + CBX(0,1,1) + CBX(1,1,1) + CBX(2,1,1) + CBX(3,1,1);
      float ix0 = bNx0 + CBX(0,2,0) + CBX(1,2,0) + CBX(2,2,0) + CBX(3,2,0);
      float ix1 = bNx1 + CBX(0,2,1) + CBX(1,2,1) + CBX(2,2,1) + CBX(3,2,1);
      float hn0 = bNh0 + CBX(0,3,0) + CBX(1,3,0) + CBX(2,3,0) + CBX(3,3,0);
      float hn1 = bNh1 + CBX(0,3,1) + CBX(1,3,1) + CBX(2,3,1) + CBX(3,3,1);
#undef CBX
      const float rg0 = 1.f / (1.f + __expf(-rp0)), rg1 = 1.f / (1.f + __expf(-rp1));
      const float zg0 = 1.f / (1.f + __expf(-zp0)), zg1 = 1.f / (1.f + __expf(-zp1));
      const float e0 = __expf(2.f * (ix0 + rg0 * hn0));
      const float e1 = __expf(2.f * (ix1 + rg1 * hn1));
      const float ng0 = 1.f - 2.f / (e0 + 1.f), ng1 = 1.f - 2.f / (e1 + 1.f);
      hr0 = ng0 + zg0 * (hr0 - ng0);
      hr1 = ng1 + zg1 * (hr1 - ng1);
    }

    // h(t+1) -> hbuf (device-scope)
    {
      char* hdst = ((t + 1) & 1) ? hs1 : hs0;
      unsigned a0 = f2bf(hr0), a1 = f2bf(hr1);
      unsigned p0 = __shfl_xor(a0, 1, 64), p1 = __shfl_xor(a1, 1, 64);
      if (!(dl & 1)) {
        st_sys_u32(hdst + rr * 1024 + ((2 * dd0) ^ SWZ(rr)), a0 | (p0 << 16));
        st_sys_u32(hdst + rr * 1024 + ((2 * dd1) ^ SWZ(rr)), a1 | (p1 << 16));
      }
    }
    // stage x(t+1) under the store-ack shadow (x region dead since bar D)
    if (t + 1 < 512) {
      char* rowb = ldsb + xr * 1536;
      bf16x8 xa, xc;
#pragma unroll
      for (int q = 0; q < 4; ++q) {
        xa[q] = (short)f2bf(xv[0][q]); xa[4 + q] = (short)f2bf(xv[1][q]);
        xc[q] = (short)f2bf(xv[2][q]); xc[4 + q] = (short)f2bf(xv[3][q]);
      }
      *(bf16x8*)(rowb + ((32 * xi) ^ SWZ(xr))) = xa;
      *(bf16x8*)(rowb + ((32 * xi + 16) ^ SWZ(xr))) = xc;
    }
    asm volatile("s_waitcnt vmcnt(0)" ::: "memory");  // h stores acked
    __syncthreads();  // E: all stores acked + x(t+1) staged
    if (tid == 192) st_sys_u32(tfl + cu, tgt + 1u);   // certify h(t+1)
    if (wv == 3) ld_sys_u32(fv, fp);                  // prime next poll
  }
#undef XPART
}

// ---- logits + masked CE + accuracy; one WG per batch row ----
__global__ __launch_bounds__(128) void logits_loss(
    const unsigned short* __restrict__ hbuf, const float* __restrict__ Wout,
    const float* __restrict__ bout, const int* __restrict__ label,
    float* __restrict__ accv) {
  __shared__ float hrow[512];
  __shared__ float lg[128];
  const int b = blockIdx.x;
  const int tm = b >> 4, r = b & 15;
  const char* base = (const char*)hbuf + (size_t)tm * 16384 + r * 1024;
  for (int i = threadIdx.x; i < 256; i += 128) {
    const char* p = base + ((i * 4) ^ SWZ(r));
    unsigned v;
    asm volatile("global_load_dword %0, %1, off sc0 sc1\n\ts_waitcnt vmcnt(0)"
                 : "=v"(v) : "v"(p) : "memory");
    hrow[2 * i] = bf2f(v & 0xffffu);
    hrow[2 * i + 1] = bf2f(v >> 16);
  }
  __syncthreads();
  const int c = threadIdx.x;
  const f32x4* w4 = (const f32x4*)(Wout + (size_t)c * 512);
  const f32x4* h4 = (const f32x4*)hrow;
  float s = bout[c];
#pragma unroll 4
  for (int i = 0; i < 128; ++i) {
    f32x4 wv = w4[i], hv = h4[i];
    s += wv[0] * hv[0] + wv[1] * hv[1] + wv[2] * hv[2] + wv[3] * hv[3];
  }
  lg[c] = s;
  __syncthreads();
  if (c == 0) {
    float mx = lg[0];
    int am = 0;
    for (int i = 1; i < 128; ++i)
      if (lg[i] > mx) { mx = lg[i]; am = i; }
    float se = 0.f;
    for (int i = 0; i < 128; ++i) se += __expf(lg[i] - mx);
    const int lb = label[b];
    const float logp = lg[lb] - mx - __logf(se);
    if (lb != 0) {
      atomicAdd(&accv[0], -logp);
      atomicAdd(&accv[1], 1.0f);
    }
    if (am == lb) atomicAdd(&accv[2], 1.0f);
  }
}

__global__ void finalize_k(const float* __restrict__ accv, float* __restrict__ out) {
  out[0] = accv[0] / fmaxf(accv[1], 1.0f);
  out[1] = accv[2] * (1.0f / 256.0f);
}

extern "C" void kernel_launch(void* const* d_in, const int* in_sizes, int n_in,
                              void* d_out, int out_size, void* d_ws, size_t ws_size,
                              hipStream_t stream) {
  (void)in_sizes; (void)n_in; (void)out_size; (void)ws_size;
  const float* x = (const float*)d_in[0];
  const int* label = (const int*)d_in[1];
  const float* h0 = (const float*)d_in[2];
  const float* Wih = (const float*)d_in[3];
  const float* Whh = (const float*)d_in[4];
  const float* bih = (const float*)d_in[5];
  const float* bhh = (const float*)d_in[6];
  const float* Wout = (const float*)d_in[7];
  const float* bout = (const float*)d_in[8];
  float* out = (float*)d_out;

  char* ws = (char*)d_ws;
  unsigned* flags = (unsigned*)ws;                      // 16 teams x 32 u32 (16 used)
  float* accv = (float*)(ws + 4096);                    // 3 accumulators
  unsigned short* hbuf = (unsigned short*)(ws + 8192);  // 2 slots x 16 teams x 16 KB

  hipMemsetAsync(ws, 0, 8192, stream);  // flags + accv: deterministic per call

  gru_persistent<<<dim3(256), dim3(256), 0, stream>>>(x, h0, Wih, Whh, bih, bhh,
                                                      flags, hbuf);
  logits_loss<<<dim3(256), dim3(128), 0, stream>>>(hbuf, Wout, bout, label, accv);
  finalize_k<<<dim3(1), dim3(1), 0, stream>>>(accv, out);
}

// Round 13
// 1316.482 us; speedup vs baseline: 2.7144x; 1.0994x over previous
//
#include <hip/hip_runtime.h>
#include <hip/hip_bf16.h>
#include <stdint.h>

// GRU: B=256, S=512, E=256, H=512, C=128
// 16 teams x 16 WGs (tm = wg&15, cu = wg>>4). Team covers batch rows
// [16tm,16tm+16); member cu owns h dims [32cu,32cu+32). 4 waves/WG split the
// fused K=768 of [x_t | h] @ [W_ih|W_hh]^T; W slice in VGPRs (144/lane).
// Sync protocol = R10 byte-for-byte (proven 1447us, absmax 0.0): sc0 sc1
// device-scope via MALL, 16 flags/team on ONE 64B line, wave 3 single-load
// polls, barriers A/D/E, tid192 post, tail prime. Pipelined polls BANNED
// (R11/R12: in-flight asm load whose dest-reg value is dead -> regalloc reuse
// -> corrupted address -> fault; __syncthreads does NOT drain asm loads).
// R13 = R10 + ONE data-path delta: DIRECT FRAGMENT GATHER.
//  * h: each lane loads its 4 MFMA A-frags straight from hbuf into registers
//    at row*1024 + ((256wv+64fh+16kg) ^ SWZ(row)) — the exact bytes the old
//    ds_read returned (hbuf bytes were copied linearly into LDS). Kills
//    ds_write + barrier B + ds_read from the post-arrival critical path.
//  * x: each lane loads its own frag slices (8 floats each) from global and
//    converts in-register (same RNE cvt as staging did -> bit-identical).
//  LDS now holds only cb. 3 barriers/step (A, D, E). FP order identical to
//  R10 => absmax must stay 0.0.

typedef __attribute__((ext_vector_type(8))) short bf16x8;
typedef __attribute__((ext_vector_type(4))) float f32x4;

#define SWZ(r) (((r)&7) << 4)

static __device__ __forceinline__ unsigned short f2bf(float f) {
  unsigned x = __builtin_bit_cast(unsigned, f);
  return (unsigned short)((x + 0x7fffu + ((x >> 16) & 1u)) >> 16);  // RNE
}
static __device__ __forceinline__ float bf2f(unsigned u) {
  return __builtin_bit_cast(float, u << 16);
}
static __device__ __forceinline__ void st_sys_u32(void* p, unsigned v) {
  asm volatile("global_store_dword %0, %1, off sc0 sc1" :: "v"(p), "v"(v) : "memory");
}
static __device__ __forceinline__ void ld_sys_u32(unsigned& d, const void* p) {
  asm volatile("global_load_dword %0, %1, off sc0 sc1" : "=v"(d) : "v"(p) : "memory");
}
static __device__ __forceinline__ bf16x8 cvt8(f32x4 a, f32x4 b) {
  bf16x8 r;
#pragma unroll
  for (int q = 0; q < 4; ++q) {
    r[q] = (short)f2bf(a[q]);
    r[4 + q] = (short)f2bf(b[q]);
  }
  return r;
}

__global__ __launch_bounds__(256, 1) void gru_persistent(
    const float* __restrict__ x, const float* __restrict__ h0,
    const float* __restrict__ Wih, const float* __restrict__ Whh,
    const float* __restrict__ bih, const float* __restrict__ bhh,
    unsigned* __restrict__ flags, unsigned short* __restrict__ hbuf) {
  __shared__ __align__(16) float cb[4 * 4 * 2 * 256];  // [wave][type][nf][row*16+col]

  const int tid = threadIdx.x, wg = blockIdx.x;
  const int tm = wg & 15, cu = wg >> 4;
  const int wv = tid >> 6, ln = tid & 63;
  const int bm = tm << 4;   // batch base
  const int d0 = cu << 5;   // h-dim slice base (32 dims)

  unsigned* tfl = flags + tm * 32;       // 16 flags on one 64B line; teams 128B apart
  const unsigned* fp = tfl + (ln & 15);
  char* hs0 = (char*)hbuf + (size_t)tm * 16384;
  char* hs1 = (char*)hbuf + 262144 + (size_t)tm * 16384;

  // ---- W slice -> VGPR bf16 B-frags (once); frag f: 0-1 = x-part, 2-5 = h-part ----
  bf16x8 BF[3][2][6];
  {
    const int j = ln & 15, kgw = ln >> 4;
#pragma unroll
    for (int g = 0; g < 3; ++g)
#pragma unroll
      for (int nf = 0; nf < 2; ++nf)
#pragma unroll
        for (int f = 0; f < 6; ++f) {
          const int R = g * 512 + d0 + nf * 16 + j;
          const float* src;
          if (f < 2) src = Wih + (size_t)R * 256 + (64 * wv + 32 * f + 8 * kgw);
          else       src = Whh + (size_t)R * 512 + (128 * wv + 32 * (f - 2) + 8 * kgw);
          bf16x8 v;
#pragma unroll
          for (int i = 0; i < 8; ++i) v[i] = (short)f2bf(src[i]);
          BF[g][nf][f] = v;
        }
  }

  const int dl = tid & 15, rr = tid >> 4;
  const int dd0 = d0 + dl, dd1 = d0 + 16 + dl;
  const float bR0 = bih[dd0] + bhh[dd0], bR1 = bih[dd1] + bhh[dd1];
  const float bZ0 = bih[512 + dd0] + bhh[512 + dd0], bZ1 = bih[512 + dd1] + bhh[512 + dd1];
  const float bNx0 = bih[1024 + dd0], bNx1 = bih[1024 + dd1];
  const float bNh0 = bhh[1024 + dd0], bNh1 = bhh[1024 + dd1];

  float hr0 = h0[(size_t)(bm + rr) * 512 + dd0];
  float hr1 = h0[(size_t)(bm + rr) * 512 + dd1];

  // ---- gather geometry (loop-invariant): lane covers A-row (ln&15), k-chunk kg ----
  const int grow = ln & 15, kg = ln >> 4;
  const int gof0 = grow * 1024 + ((256 * wv + 0 + 16 * kg) ^ SWZ(grow));
  const int gof1 = grow * 1024 + ((256 * wv + 64 + 16 * kg) ^ SWZ(grow));
  const int gof2 = grow * 1024 + ((256 * wv + 128 + 16 * kg) ^ SWZ(grow));
  const int gof3 = grow * 1024 + ((256 * wv + 192 + 16 * kg) ^ SWZ(grow));
  // x frag base: row (bm+grow), floats [64wv+8kg .. ) ; frag fx adds 32*fx
  const float* xlane = x + (size_t)(bm + grow) * 512 * 256 + 64 * wv + 8 * kg;

  // ---- prologue: h(0) -> slot0 (identical R10); x(0) -> regs -> bf16 frags ----
  {
    unsigned a0 = f2bf(hr0), a1 = f2bf(hr1);
    unsigned p0 = __shfl_xor(a0, 1, 64), p1 = __shfl_xor(a1, 1, 64);
    if (!(dl & 1)) {
      st_sys_u32(hs0 + rr * 1024 + ((2 * dd0) ^ SWZ(rr)), a0 | (p0 << 16));
      st_sys_u32(hs0 + rr * 1024 + ((2 * dd1) ^ SWZ(rr)), a1 | (p1 << 16));
    }
  }
  f32x4 xn0a = *(const f32x4*)(xlane + 0);
  f32x4 xn0b = *(const f32x4*)(xlane + 4);
  f32x4 xn1a = *(const f32x4*)(xlane + 32);
  f32x4 xn1b = *(const f32x4*)(xlane + 36);
  bf16x8 xf0 = cvt8(xn0a, xn0b);
  bf16x8 xf1 = cvt8(xn1a, xn1b);

  asm volatile("s_waitcnt vmcnt(0)" ::: "memory");  // h0 stores acked
  __syncthreads();                                  // E0
  if (tid == 192) st_sys_u32(tfl + cu, 1u);         // certify h(0)
  unsigned fv = 0;
  if (wv == 3) ld_sys_u32(fv, fp);                  // prime first poll

  for (int t = 0; t < 512; ++t) {
    const unsigned tgt = (unsigned)(t + 1);
    f32x4 aR[2] = {}, aZ[2] = {}, aNx[2] = {}, aNh[2] = {};

    // x-part MFMA from register frags (per-acc order fx0 then fx1 — R10-identical)
#define XPART()                                                                          \
  {                                                                                      \
    _Pragma("unroll")                                                                    \
    for (int nf = 0; nf < 2; ++nf) {                                                     \
      aR[nf]  = __builtin_amdgcn_mfma_f32_16x16x32_bf16(xf0, BF[0][nf][0], aR[nf], 0, 0, 0);  \
      aZ[nf]  = __builtin_amdgcn_mfma_f32_16x16x32_bf16(xf0, BF[1][nf][0], aZ[nf], 0, 0, 0);  \
      aNx[nf] = __builtin_amdgcn_mfma_f32_16x16x32_bf16(xf0, BF[2][nf][0], aNx[nf], 0, 0, 0); \
      aR[nf]  = __builtin_amdgcn_mfma_f32_16x16x32_bf16(xf1, BF[0][nf][1], aR[nf], 0, 0, 0);  \
      aZ[nf]  = __builtin_amdgcn_mfma_f32_16x16x32_bf16(xf1, BF[1][nf][1], aZ[nf], 0, 0, 0);  \
      aNx[nf] = __builtin_amdgcn_mfma_f32_16x16x32_bf16(xf1, BF[2][nf][1], aNx[nf], 0, 0, 0); \
    }                                                                                    \
  }

    if (wv == 3) {
      // R10's exact single-load poll (drain prime, then load+wait per round)
      asm volatile("s_waitcnt vmcnt(0)" : "+v"(fv) :: "memory");
      while (__ballot(fv >= tgt) != ~0ull) {
        asm volatile("global_load_dword %0, %1, off sc0 sc1\n\ts_waitcnt vmcnt(0)"
                     : "=v"(fv) : "v"(fp) : "memory");
      }
    } else {
      XPART();  // waves 0-2: x-MFMA under the poll
    }
    __syncthreads();  // A: h(t) certified for the whole WG

    // ---- direct h-frag gathers (device-scope): regs, no LDS hop ----
    const char* hsrc = (t & 1) ? hs1 : hs0;
    f32x4 g0, g1, g2, g3;
    asm volatile("global_load_dwordx4 %0, %1, off sc0 sc1"
                 : "=v"(g0) : "v"(hsrc + gof0) : "memory");
    asm volatile("global_load_dwordx4 %0, %1, off sc0 sc1"
                 : "=v"(g1) : "v"(hsrc + gof1) : "memory");
    asm volatile("global_load_dwordx4 %0, %1, off sc0 sc1"
                 : "=v"(g2) : "v"(hsrc + gof2) : "memory");
    asm volatile("global_load_dwordx4 %0, %1, off sc0 sc1"
                 : "=v"(g3) : "v"(hsrc + gof3) : "memory");

    if (wv == 3) { XPART(); }  // wave 3: x-MFMA under its own gather RT
    __builtin_amdgcn_sched_barrier(0);  // pin x-MFMA BEFORE the drain

    asm volatile("s_waitcnt vmcnt(0)"
                 : "+v"(g0), "+v"(g1), "+v"(g2), "+v"(g3) :: "memory");
    const bf16x8 hf0 = __builtin_bit_cast(bf16x8, g0);
    const bf16x8 hf1 = __builtin_bit_cast(bf16x8, g1);
    const bf16x8 hf2 = __builtin_bit_cast(bf16x8, g2);
    const bf16x8 hf3 = __builtin_bit_cast(bf16x8, g3);

    // x(t+1) prefetch (plain loads; compiler-managed waits; consumed at tail cvt)
    if (t + 1 < 512) {
      const float* xb2 = xlane + (size_t)(t + 1) * 256;
      xn0a = *(const f32x4*)(xb2 + 0);
      xn0b = *(const f32x4*)(xb2 + 4);
      xn1a = *(const f32x4*)(xb2 + 32);
      xn1b = *(const f32x4*)(xb2 + 36);
    }

    // ---- h-part MFMA (4 frags, register operands; per-acc order fh0..3) ----
#pragma unroll
    for (int nf = 0; nf < 2; ++nf) {
      aR[nf]  = __builtin_amdgcn_mfma_f32_16x16x32_bf16(hf0, BF[0][nf][2], aR[nf], 0, 0, 0);
      aZ[nf]  = __builtin_amdgcn_mfma_f32_16x16x32_bf16(hf0, BF[1][nf][2], aZ[nf], 0, 0, 0);
      aNh[nf] = __builtin_amdgcn_mfma_f32_16x16x32_bf16(hf0, BF[2][nf][2], aNh[nf], 0, 0, 0);
      aR[nf]  = __builtin_amdgcn_mfma_f32_16x16x32_bf16(hf1, BF[0][nf][3], aR[nf], 0, 0, 0);
      aZ[nf]  = __builtin_amdgcn_mfma_f32_16x16x32_bf16(hf1, BF[1][nf][3], aZ[nf], 0, 0, 0);
      aNh[nf] = __builtin_amdgcn_mfma_f32_16x16x32_bf16(hf1, BF[2][nf][3], aNh[nf], 0, 0, 0);
      aR[nf]  = __builtin_amdgcn_mfma_f32_16x16x32_bf16(hf2, BF[0][nf][4], aR[nf], 0, 0, 0);
      aZ[nf]  = __builtin_amdgcn_mfma_f32_16x16x32_bf16(hf2, BF[1][nf][4], aZ[nf], 0, 0, 0);
      aNh[nf] = __builtin_amdgcn_mfma_f32_16x16x32_bf16(hf2, BF[2][nf][4], aNh[nf], 0, 0, 0);
      aR[nf]  = __builtin_amdgcn_mfma_f32_16x16x32_bf16(hf3, BF[0][nf][5], aR[nf], 0, 0, 0);
      aZ[nf]  = __builtin_amdgcn_mfma_f32_16x16x32_bf16(hf3, BF[1][nf][5], aZ[nf], 0, 0, 0);
      aNh[nf] = __builtin_amdgcn_mfma_f32_16x16x32_bf16(hf3, BF[2][nf][5], aNh[nf], 0, 0, 0);
    }

    // ---- partials -> cbuf (identical R10) ----
    {
      const int cc = ln & 15, cg = ln >> 4;
#pragma unroll
      for (int nf = 0; nf < 2; ++nf)
#pragma unroll
        for (int i = 0; i < 4; ++i) {
          const int row = cg * 4 + i;
          cb[((wv * 4 + 0) * 2 + nf) * 256 + row * 16 + cc] = aR[nf][i];
          cb[((wv * 4 + 1) * 2 + nf) * 256 + row * 16 + cc] = aZ[nf][i];
          cb[((wv * 4 + 2) * 2 + nf) * 256 + row * 16 + cc] = aNx[nf][i];
          cb[((wv * 4 + 3) * 2 + nf) * 256 + row * 16 + cc] = aNh[nf][i];
        }
    }
    __syncthreads();  // D

    // ---- combine + gates (fp32, identical R10) ----
    {
#define CBX(w, ty, nf) cb[(((w) * 4 + (ty)) * 2 + (nf)) * 256 + rr * 16 + dl]
      float rp0 = bR0 + CBX(0,0,0) + CBX(1,0,0) + CBX(2,0,0) + CBX(3,0,0);
      float rp1 = bR1 + CBX(0,0,1) + CBX(1,0,1) + CBX(2,0,1) + CBX(3,0,1);
      float zp0 = bZ0 + CBX(0,1,0) + CBX(1,1,0) + CBX(2,1,0) + CBX(3,1,0);
      float zp1 = bZ1 + CBX(0,1,1) + CBX(1,1,1) + CBX(2,1,1) + CBX(3,1,1);
      float ix0 = bNx0 + CBX(0,2,0) + CBX(1,2,0) + CBX(2,2,0) + CBX(3,2,0);
      float ix1 = bNx1 + CBX(0,2,1) + CBX(1,2,1) + CBX(2,2,1) + CBX(3,2,1);
      float hn0 = bNh0 + CBX(0,3,0) + CBX(1,3,0) + CBX(2,3,0) + CBX(3,3,0);
      float hn1 = bNh1 + CBX(0,3,1) + CBX(1,3,1) + CBX(2,3,1) + CBX(3,3,1);
#undef CBX
      const float rg0 = 1.f / (1.f + __expf(-rp0)), rg1 = 1.f / (1.f + __expf(-rp1));
      const float zg0 = 1.f / (1.f + __expf(-zp0)), zg1 = 1.f / (1.f + __expf(-zp1));
      const float e0 = __expf(2.f * (ix0 + rg0 * hn0));
      const float e1 = __expf(2.f * (ix1 + rg1 * hn1));
      const float ng0 = 1.f - 2.f / (e0 + 1.f), ng1 = 1.f - 2.f / (e1 + 1.f);
      hr0 = ng0 + zg0 * (hr0 - ng0);
      hr1 = ng1 + zg1 * (hr1 - ng1);
    }

    // ---- h(t+1) -> hbuf (device-scope, identical R10) ----
    {
      char* hdst = ((t + 1) & 1) ? hs1 : hs0;
      unsigned a0 = f2bf(hr0), a1 = f2bf(hr1);
      unsigned p0 = __shfl_xor(a0, 1, 64), p1 = __shfl_xor(a1, 1, 64);
      if (!(dl & 1)) {
        st_sys_u32(hdst + rr * 1024 + ((2 * dd0) ^ SWZ(rr)), a0 | (p0 << 16));
        st_sys_u32(hdst + rr * 1024 + ((2 * dd1) ^ SWZ(rr)), a1 | (p1 << 16));
      }
    }
    // cvt x(t+1) frags in the store-ack shadow (compiler waits on the plain loads)
    if (t + 1 < 512) {
      xf0 = cvt8(xn0a, xn0b);
      xf1 = cvt8(xn1a, xn1b);
    }
    asm volatile("s_waitcnt vmcnt(0)" ::: "memory");  // h stores acked
    __syncthreads();  // E
    if (tid == 192) st_sys_u32(tfl + cu, tgt + 1u);   // certify h(t+1)
    if (wv == 3) ld_sys_u32(fv, fp);                  // prime next poll
  }
#undef XPART
}

// ---- logits + masked CE + accuracy; one WG per batch row ----
__global__ __launch_bounds__(128) void logits_loss(
    const unsigned short* __restrict__ hbuf, const float* __restrict__ Wout,
    const float* __restrict__ bout, const int* __restrict__ label,
    float* __restrict__ accv) {
  __shared__ float hrow[512];
  __shared__ float lg[128];
  const int b = blockIdx.x;
  const int tm = b >> 4, r = b & 15;
  const char* base = (const char*)hbuf + (size_t)tm * 16384 + r * 1024;
  for (int i = threadIdx.x; i < 256; i += 128) {
    const char* p = base + ((i * 4) ^ SWZ(r));
    unsigned v;
    asm volatile("global_load_dword %0, %1, off sc0 sc1\n\ts_waitcnt vmcnt(0)"
                 : "=v"(v) : "v"(p) : "memory");
    hrow[2 * i] = bf2f(v & 0xffffu);
    hrow[2 * i + 1] = bf2f(v >> 16);
  }
  __syncthreads();
  const int c = threadIdx.x;
  const f32x4* w4 = (const f32x4*)(Wout + (size_t)c * 512);
  const f32x4* h4 = (const f32x4*)hrow;
  float s = bout[c];
#pragma unroll 4
  for (int i = 0; i < 128; ++i) {
    f32x4 wv = w4[i], hv = h4[i];
    s += wv[0] * hv[0] + wv[1] * hv[1] + wv[2] * hv[2] + wv[3] * hv[3];
  }
  lg[c] = s;
  __syncthreads();
  if (c == 0) {
    float mx = lg[0];
    int am = 0;
    for (int i = 1; i < 128; ++i)
      if (lg[i] > mx) { mx = lg[i]; am = i; }
    float se = 0.f;
    for (int i = 0; i < 128; ++i) se += __expf(lg[i] - mx);
    const int lb = label[b];
    const float logp = lg[lb] - mx - __logf(se);
    if (lb != 0) {
      atomicAdd(&accv[0], -logp);
      atomicAdd(&accv[1], 1.0f);
    }
    if (am == lb) atomicAdd(&accv[2], 1.0f);
  }
}

__global__ void finalize_k(const float* __restrict__ accv, float* __restrict__ out) {
  out[0] = accv[0] / fmaxf(accv[1], 1.0f);
  out[1] = accv[2] * (1.0f / 256.0f);
}

extern "C" void kernel_launch(void* const* d_in, const int* in_sizes, int n_in,
                              void* d_out, int out_size, void* d_ws, size_t ws_size,
                              hipStream_t stream) {
  (void)in_sizes; (void)n_in; (void)out_size; (void)ws_size;
  const float* x = (const float*)d_in[0];
  const int* label = (const int*)d_in[1];
  const float* h0 = (const float*)d_in[2];
  const float* Wih = (const float*)d_in[3];
  const float* Whh = (const float*)d_in[4];
  const float* bih = (const float*)d_in[5];
  const float* bhh = (const float*)d_in[6];
  const float* Wout = (const float*)d_in[7];
  const float* bout = (const float*)d_in[8];
  float* out = (float*)d_out;

  char* ws = (char*)d_ws;
  unsigned* flags = (unsigned*)ws;                      // 16 teams x 32 u32 (16 used)
  float* accv = (float*)(ws + 4096);                    // 3 accumulators
  unsigned short* hbuf = (unsigned short*)(ws + 8192);  // 2 slots x 16 teams x 16 KB

  hipMemsetAsync(ws, 0, 8192, stream);  // flags + accv: deterministic per call

  gru_persistent<<<dim3(256), dim3(256), 0, stream>>>(x, h0, Wih, Whh, bih, bhh,
                                                      flags, hbuf);
  logits_loss<<<dim3(256), dim3(128), 0, stream>>>(hbuf, Wout, bout, label, accv);
  finalize_k<<<dim3(1), dim3(1), 0, stream>>>(accv, out);
}

// Round 14
// 1226.590 us; speedup vs baseline: 2.9133x; 1.0733x over previous
//
#include <hip/hip_runtime.h>
#include <hip/hip_bf16.h>
#include <stdint.h>

// GRU: B=256, S=512, E=256, H=512, C=128
// 16 teams x 16 WGs (tm = wg&15, cu = wg>>4). Team covers batch rows
// [16tm,16tm+16); member cu owns h dims [32cu,32cu+32). 4 waves/WG split the
// fused K=768 of [x_t | h] @ [W_ih|W_hh]^T; W slice in VGPRs (144/lane).
// Sync protocol = R10/R13 (proven 1316us, absmax 0.0): 16 flags/team on ONE
// 64B line, wave 3 single-load polls (pipelined polls BANNED — R12 fault),
// barriers A/D/E, tid192 post, tail prime, direct h-frag gathers (R13).
// R14 = R13 + ONE delta: MALL-RESIDENT PRODUCER WRITES.
//  * All protocol writes (h data, flags) use RETURNLESS global_atomic_swap
//    instead of global_store sc0 sc1. Device-scope atomics execute at the
//    coherency point (MALL) and leave the line dirty there — no HBM
//    write-through on the ack path. R13's counters showed WRITE_SIZE==h bytes
//    (stores went to HBM; ack ~1300cy); atomics should cut ack to MALL-class
//    (~700cy) and collapse WRITE_SIZE to evictions only.
//  * Consumers unchanged: sc0 sc1 loads read MALL -> see dirty lines.
//  Same bytes, same order, same vmcnt semantics => absmax stays 0.0.

typedef __attribute__((ext_vector_type(8))) short bf16x8;
typedef __attribute__((ext_vector_type(4))) float f32x4;

#define SWZ(r) (((r)&7) << 4)

static __device__ __forceinline__ unsigned short f2bf(float f) {
  unsigned x = __builtin_bit_cast(unsigned, f);
  return (unsigned short)((x + 0x7fffu + ((x >> 16) & 1u)) >> 16);  // RNE
}
static __device__ __forceinline__ float bf2f(unsigned u) {
  return __builtin_bit_cast(float, u << 16);
}
// MALL-resident write: returnless device-scope atomic swap (performed at MALL,
// line left dirty in MALL; counts vmcnt; no HBM write-through on ack path).
static __device__ __forceinline__ void st_mall_u32(void* p, unsigned v) {
  asm volatile("global_atomic_swap %0, %1, off" :: "v"(p), "v"(v) : "memory");
}
static __device__ __forceinline__ void ld_sys_u32(unsigned& d, const void* p) {
  asm volatile("global_load_dword %0, %1, off sc0 sc1" : "=v"(d) : "v"(p) : "memory");
}
static __device__ __forceinline__ bf16x8 cvt8(f32x4 a, f32x4 b) {
  bf16x8 r;
#pragma unroll
  for (int q = 0; q < 4; ++q) {
    r[q] = (short)f2bf(a[q]);
    r[4 + q] = (short)f2bf(b[q]);
  }
  return r;
}

__global__ __launch_bounds__(256, 1) void gru_persistent(
    const float* __restrict__ x, const float* __restrict__ h0,
    const float* __restrict__ Wih, const float* __restrict__ Whh,
    const float* __restrict__ bih, const float* __restrict__ bhh,
    unsigned* __restrict__ flags, unsigned short* __restrict__ hbuf) {
  __shared__ __align__(16) float cb[4 * 4 * 2 * 256];  // [wave][type][nf][row*16+col]

  const int tid = threadIdx.x, wg = blockIdx.x;
  const int tm = wg & 15, cu = wg >> 4;
  const int wv = tid >> 6, ln = tid & 63;
  const int bm = tm << 4;   // batch base
  const int d0 = cu << 5;   // h-dim slice base (32 dims)

  unsigned* tfl = flags + tm * 32;       // 16 flags on one 64B line; teams 128B apart
  const unsigned* fp = tfl + (ln & 15);
  char* hs0 = (char*)hbuf + (size_t)tm * 16384;
  char* hs1 = (char*)hbuf + 262144 + (size_t)tm * 16384;

  // ---- W slice -> VGPR bf16 B-frags (once); frag f: 0-1 = x-part, 2-5 = h-part ----
  bf16x8 BF[3][2][6];
  {
    const int j = ln & 15, kgw = ln >> 4;
#pragma unroll
    for (int g = 0; g < 3; ++g)
#pragma unroll
      for (int nf = 0; nf < 2; ++nf)
#pragma unroll
        for (int f = 0; f < 6; ++f) {
          const int R = g * 512 + d0 + nf * 16 + j;
          const float* src;
          if (f < 2) src = Wih + (size_t)R * 256 + (64 * wv + 32 * f + 8 * kgw);
          else       src = Whh + (size_t)R * 512 + (128 * wv + 32 * (f - 2) + 8 * kgw);
          bf16x8 v;
#pragma unroll
          for (int i = 0; i < 8; ++i) v[i] = (short)f2bf(src[i]);
          BF[g][nf][f] = v;
        }
  }

  const int dl = tid & 15, rr = tid >> 4;
  const int dd0 = d0 + dl, dd1 = d0 + 16 + dl;
  const float bR0 = bih[dd0] + bhh[dd0], bR1 = bih[dd1] + bhh[dd1];
  const float bZ0 = bih[512 + dd0] + bhh[512 + dd0], bZ1 = bih[512 + dd1] + bhh[512 + dd1];
  const float bNx0 = bih[1024 + dd0], bNx1 = bih[1024 + dd1];
  const float bNh0 = bhh[1024 + dd0], bNh1 = bhh[1024 + dd1];

  float hr0 = h0[(size_t)(bm + rr) * 512 + dd0];
  float hr1 = h0[(size_t)(bm + rr) * 512 + dd1];

  // ---- gather geometry (loop-invariant): lane covers A-row (ln&15), k-chunk kg ----
  const int grow = ln & 15, kg = ln >> 4;
  const int gof0 = grow * 1024 + ((256 * wv + 0 + 16 * kg) ^ SWZ(grow));
  const int gof1 = grow * 1024 + ((256 * wv + 64 + 16 * kg) ^ SWZ(grow));
  const int gof2 = grow * 1024 + ((256 * wv + 128 + 16 * kg) ^ SWZ(grow));
  const int gof3 = grow * 1024 + ((256 * wv + 192 + 16 * kg) ^ SWZ(grow));
  // x frag base: row (bm+grow), floats [64wv+8kg .. ) ; frag fx adds 32*fx
  const float* xlane = x + (size_t)(bm + grow) * 512 * 256 + 64 * wv + 8 * kg;

  // ---- prologue: h(0) -> slot0 (MALL writes); x(0) -> regs -> bf16 frags ----
  {
    unsigned a0 = f2bf(hr0), a1 = f2bf(hr1);
    unsigned p0 = __shfl_xor(a0, 1, 64), p1 = __shfl_xor(a1, 1, 64);
    if (!(dl & 1)) {
      st_mall_u32(hs0 + rr * 1024 + ((2 * dd0) ^ SWZ(rr)), a0 | (p0 << 16));
      st_mall_u32(hs0 + rr * 1024 + ((2 * dd1) ^ SWZ(rr)), a1 | (p1 << 16));
    }
  }
  f32x4 xn0a = *(const f32x4*)(xlane + 0);
  f32x4 xn0b = *(const f32x4*)(xlane + 4);
  f32x4 xn1a = *(const f32x4*)(xlane + 32);
  f32x4 xn1b = *(const f32x4*)(xlane + 36);
  bf16x8 xf0 = cvt8(xn0a, xn0b);
  bf16x8 xf1 = cvt8(xn1a, xn1b);

  asm volatile("s_waitcnt vmcnt(0)" ::: "memory");  // h0 writes performed at MALL
  __syncthreads();                                  // E0
  if (tid == 192) st_mall_u32(tfl + cu, 1u);        // certify h(0)
  unsigned fv = 0;
  if (wv == 3) ld_sys_u32(fv, fp);                  // prime first poll

  for (int t = 0; t < 512; ++t) {
    const unsigned tgt = (unsigned)(t + 1);
    f32x4 aR[2] = {}, aZ[2] = {}, aNx[2] = {}, aNh[2] = {};

    // x-part MFMA from register frags (per-acc order fx0 then fx1 — R13-identical)
#define XPART()                                                                          \
  {                                                                                      \
    _Pragma("unroll")                                                                    \
    for (int nf = 0; nf < 2; ++nf) {                                                     \
      aR[nf]  = __builtin_amdgcn_mfma_f32_16x16x32_bf16(xf0, BF[0][nf][0], aR[nf], 0, 0, 0);  \
      aZ[nf]  = __builtin_amdgcn_mfma_f32_16x16x32_bf16(xf0, BF[1][nf][0], aZ[nf], 0, 0, 0);  \
      aNx[nf] = __builtin_amdgcn_mfma_f32_16x16x32_bf16(xf0, BF[2][nf][0], aNx[nf], 0, 0, 0); \
      aR[nf]  = __builtin_amdgcn_mfma_f32_16x16x32_bf16(xf1, BF[0][nf][1], aR[nf], 0, 0, 0);  \
      aZ[nf]  = __builtin_amdgcn_mfma_f32_16x16x32_bf16(xf1, BF[1][nf][1], aZ[nf], 0, 0, 0);  \
      aNx[nf] = __builtin_amdgcn_mfma_f32_16x16x32_bf16(xf1, BF[2][nf][1], aNx[nf], 0, 0, 0); \
    }                                                                                    \
  }

    if (wv == 3) {
      // R10's exact single-load poll (drain prime, then load+wait per round)
      asm volatile("s_waitcnt vmcnt(0)" : "+v"(fv) :: "memory");
      while (__ballot(fv >= tgt) != ~0ull) {
        asm volatile("global_load_dword %0, %1, off sc0 sc1\n\ts_waitcnt vmcnt(0)"
                     : "=v"(fv) : "v"(fp) : "memory");
      }
    } else {
      XPART();  // waves 0-2: x-MFMA under the poll
    }
    __syncthreads();  // A: h(t) certified for the whole WG

    // ---- direct h-frag gathers (device-scope): regs, no LDS hop ----
    const char* hsrc = (t & 1) ? hs1 : hs0;
    f32x4 g0, g1, g2, g3;
    asm volatile("global_load_dwordx4 %0, %1, off sc0 sc1"
                 : "=v"(g0) : "v"(hsrc + gof0) : "memory");
    asm volatile("global_load_dwordx4 %0, %1, off sc0 sc1"
                 : "=v"(g1) : "v"(hsrc + gof1) : "memory");
    asm volatile("global_load_dwordx4 %0, %1, off sc0 sc1"
                 : "=v"(g2) : "v"(hsrc + gof2) : "memory");
    asm volatile("global_load_dwordx4 %0, %1, off sc0 sc1"
                 : "=v"(g3) : "v"(hsrc + gof3) : "memory");

    if (wv == 3) { XPART(); }  // wave 3: x-MFMA under its own gather RT
    __builtin_amdgcn_sched_barrier(0);  // pin x-MFMA BEFORE the drain

    asm volatile("s_waitcnt vmcnt(0)"
                 : "+v"(g0), "+v"(g1), "+v"(g2), "+v"(g3) :: "memory");
    const bf16x8 hf0 = __builtin_bit_cast(bf16x8, g0);
    const bf16x8 hf1 = __builtin_bit_cast(bf16x8, g1);
    const bf16x8 hf2 = __builtin_bit_cast(bf16x8, g2);
    const bf16x8 hf3 = __builtin_bit_cast(bf16x8, g3);

    // x(t+1) prefetch (plain loads; compiler-managed waits; consumed at tail cvt)
    if (t + 1 < 512) {
      const float* xb2 = xlane + (size_t)(t + 1) * 256;
      xn0a = *(const f32x4*)(xb2 + 0);
      xn0b = *(const f32x4*)(xb2 + 4);
      xn1a = *(const f32x4*)(xb2 + 32);
      xn1b = *(const f32x4*)(xb2 + 36);
    }

    // ---- h-part MFMA (4 frags, register operands; per-acc order fh0..3) ----
#pragma unroll
    for (int nf = 0; nf < 2; ++nf) {
      aR[nf]  = __builtin_amdgcn_mfma_f32_16x16x32_bf16(hf0, BF[0][nf][2], aR[nf], 0, 0, 0);
      aZ[nf]  = __builtin_amdgcn_mfma_f32_16x16x32_bf16(hf0, BF[1][nf][2], aZ[nf], 0, 0, 0);
      aNh[nf] = __builtin_amdgcn_mfma_f32_16x16x32_bf16(hf0, BF[2][nf][2], aNh[nf], 0, 0, 0);
      aR[nf]  = __builtin_amdgcn_mfma_f32_16x16x32_bf16(hf1, BF[0][nf][3], aR[nf], 0, 0, 0);
      aZ[nf]  = __builtin_amdgcn_mfma_f32_16x16x32_bf16(hf1, BF[1][nf][3], aZ[nf], 0, 0, 0);
      aNh[nf] = __builtin_amdgcn_mfma_f32_16x16x32_bf16(hf1, BF[2][nf][3], aNh[nf], 0, 0, 0);
      aR[nf]  = __builtin_amdgcn_mfma_f32_16x16x32_bf16(hf2, BF[0][nf][4], aR[nf], 0, 0, 0);
      aZ[nf]  = __builtin_amdgcn_mfma_f32_16x16x32_bf16(hf2, BF[1][nf][4], aZ[nf], 0, 0, 0);
      aNh[nf] = __builtin_amdgcn_mfma_f32_16x16x32_bf16(hf2, BF[2][nf][4], aNh[nf], 0, 0, 0);
      aR[nf]  = __builtin_amdgcn_mfma_f32_16x16x32_bf16(hf3, BF[0][nf][5], aR[nf], 0, 0, 0);
      aZ[nf]  = __builtin_amdgcn_mfma_f32_16x16x32_bf16(hf3, BF[1][nf][5], aZ[nf], 0, 0, 0);
      aNh[nf] = __builtin_amdgcn_mfma_f32_16x16x32_bf16(hf3, BF[2][nf][5], aNh[nf], 0, 0, 0);
    }

    // ---- partials -> cbuf (identical R13) ----
    {
      const int cc = ln & 15, cg = ln >> 4;
#pragma unroll
      for (int nf = 0; nf < 2; ++nf)
#pragma unroll
        for (int i = 0; i < 4; ++i) {
          const int row = cg * 4 + i;
          cb[((wv * 4 + 0) * 2 + nf) * 256 + row * 16 + cc] = aR[nf][i];
          cb[((wv * 4 + 1) * 2 + nf) * 256 + row * 16 + cc] = aZ[nf][i];
          cb[((wv * 4 + 2) * 2 + nf) * 256 + row * 16 + cc] = aNx[nf][i];
          cb[((wv * 4 + 3) * 2 + nf) * 256 + row * 16 + cc] = aNh[nf][i];
        }
    }
    __syncthreads();  // D

    // ---- combine + gates (fp32, identical R13) ----
    {
#define CBX(w, ty, nf) cb[(((w) * 4 + (ty)) * 2 + (nf)) * 256 + rr * 16 + dl]
      float rp0 = bR0 + CBX(0,0,0) + CBX(1,0,0) + CBX(2,0,0) + CBX(3,0,0);
      float rp1 = bR1 + CBX(0,0,1) + CBX(1,0,1) + CBX(2,0,1) + CBX(3,0,1);
      float zp0 = bZ0 + CBX(0,1,0) + CBX(1,1,0) + CBX(2,1,0) + CBX(3,1,0);
      float zp1 = bZ1 + CBX(0,1,1) + CBX(1,1,1) + CBX(2,1,1) + CBX(3,1,1);
      float ix0 = bNx0 + CBX(0,2,0) + CBX(1,2,0) + CBX(2,2,0) + CBX(3,2,0);
      float ix1 = bNx1 + CBX(0,2,1) + CBX(1,2,1) + CBX(2,2,1) + CBX(3,2,1);
      float hn0 = bNh0 + CBX(0,3,0) + CBX(1,3,0) + CBX(2,3,0) + CBX(3,3,0);
      float hn1 = bNh1 + CBX(0,3,1) + CBX(1,3,1) + CBX(2,3,1) + CBX(3,3,1);
#undef CBX
      const float rg0 = 1.f / (1.f + __expf(-rp0)), rg1 = 1.f / (1.f + __expf(-rp1));
      const float zg0 = 1.f / (1.f + __expf(-zp0)), zg1 = 1.f / (1.f + __expf(-zp1));
      const float e0 = __expf(2.f * (ix0 + rg0 * hn0));
      const float e1 = __expf(2.f * (ix1 + rg1 * hn1));
      const float ng0 = 1.f - 2.f / (e0 + 1.f), ng1 = 1.f - 2.f / (e1 + 1.f);
      hr0 = ng0 + zg0 * (hr0 - ng0);
      hr1 = ng1 + zg1 * (hr1 - ng1);
    }

    // ---- h(t+1) -> hbuf (MALL-resident atomic writes) ----
    {
      char* hdst = ((t + 1) & 1) ? hs1 : hs0;
      unsigned a0 = f2bf(hr0), a1 = f2bf(hr1);
      unsigned p0 = __shfl_xor(a0, 1, 64), p1 = __shfl_xor(a1, 1, 64);
      if (!(dl & 1)) {
        st_mall_u32(hdst + rr * 1024 + ((2 * dd0) ^ SWZ(rr)), a0 | (p0 << 16));
        st_mall_u32(hdst + rr * 1024 + ((2 * dd1) ^ SWZ(rr)), a1 | (p1 << 16));
      }
    }
    // cvt x(t+1) frags in the ack shadow (compiler waits on the plain loads)
    if (t + 1 < 512) {
      xf0 = cvt8(xn0a, xn0b);
      xf1 = cvt8(xn1a, xn1b);
    }
    asm volatile("s_waitcnt vmcnt(0)" ::: "memory");  // h writes performed at MALL
    __syncthreads();  // E
    if (tid == 192) st_mall_u32(tfl + cu, tgt + 1u);  // certify h(t+1)
    if (wv == 3) ld_sys_u32(fv, fp);                  // prime next poll
  }
#undef XPART
}

// ---- logits + masked CE + accuracy; one WG per batch row ----
__global__ __launch_bounds__(128) void logits_loss(
    const unsigned short* __restrict__ hbuf, const float* __restrict__ Wout,
    const float* __restrict__ bout, const int* __restrict__ label,
    float* __restrict__ accv) {
  __shared__ float hrow[512];
  __shared__ float lg[128];
  const int b = blockIdx.x;
  const int tm = b >> 4, r = b & 15;
  const char* base = (const char*)hbuf + (size_t)tm * 16384 + r * 1024;
  for (int i = threadIdx.x; i < 256; i += 128) {
    const char* p = base + ((i * 4) ^ SWZ(r));
    unsigned v;
    asm volatile("global_load_dword %0, %1, off sc0 sc1\n\ts_waitcnt vmcnt(0)"
                 : "=v"(v) : "v"(p) : "memory");
    hrow[2 * i] = bf2f(v & 0xffffu);
    hrow[2 * i + 1] = bf2f(v >> 16);
  }
  __syncthreads();
  const int c = threadIdx.x;
  const f32x4* w4 = (const f32x4*)(Wout + (size_t)c * 512);
  const f32x4* h4 = (const f32x4*)hrow;
  float s = bout[c];
#pragma unroll 4
  for (int i = 0; i < 128; ++i) {
    f32x4 wv = w4[i], hv = h4[i];
    s += wv[0] * hv[0] + wv[1] * hv[1] + wv[2] * hv[2] + wv[3] * hv[3];
  }
  lg[c] = s;
  __syncthreads();
  if (c == 0) {
    float mx = lg[0];
    int am = 0;
    for (int i = 1; i < 128; ++i)
      if (lg[i] > mx) { mx = lg[i]; am = i; }
    float se = 0.f;
    for (int i = 0; i < 128; ++i) se += __expf(lg[i] - mx);
    const int lb = label[b];
    const float logp = lg[lb] - mx - __logf(se);
    if (lb != 0) {
      atomicAdd(&accv[0], -logp);
      atomicAdd(&accv[1], 1.0f);
    }
    if (am == lb) atomicAdd(&accv[2], 1.0f);
  }
}

__global__ void finalize_k(const float* __restrict__ accv, float* __restrict__ out) {
  out[0] = accv[0] / fmaxf(accv[1], 1.0f);
  out[1] = accv[2] * (1.0f / 256.0f);
}

extern "C" void kernel_launch(void* const* d_in, const int* in_sizes, int n_in,
                              void* d_out, int out_size, void* d_ws, size_t ws_size,
                              hipStream_t stream) {
  (void)in_sizes; (void)n_in; (void)out_size; (void)ws_size;
  const float* x = (const float*)d_in[0];
  const int* label = (const int*)d_in[1];
  const float* h0 = (const float*)d_in[2];
  const float* Wih = (const float*)d_in[3];
  const float* Whh = (const float*)d_in[4];
  const float* bih = (const float*)d_in[5];
  const float* bhh = (const float*)d_in[6];
  const float* Wout = (const float*)d_in[7];
  const float* bout = (const float*)d_in[8];
  float* out = (float*)d_out;

  char* ws = (char*)d_ws;
  unsigned* flags = (unsigned*)ws;                      // 16 teams x 32 u32 (16 used)
  float* accv = (float*)(ws + 4096);                    // 3 accumulators
  unsigned short* hbuf = (unsigned short*)(ws + 8192);  // 2 slots x 16 teams x 16 KB

  hipMemsetAsync(ws, 0, 8192, stream);  // flags + accv: deterministic per call

  gru_persistent<<<dim3(256), dim3(256), 0, stream>>>(x, h0, Wih, Whh, bih, bhh,
                                                      flags, hbuf);
  logits_loss<<<dim3(256), dim3(128), 0, stream>>>(hbuf, Wout, bout, label, accv);
  finalize_k<<<dim3(1), dim3(1), 0, stream>>>(accv, out);
}